// Round 5
// baseline (109.355 us; speedup 1.0000x reference)
//
#include <hip/hip_runtime.h>
#include <math.h>

// Problem constants (Occ3D-nuScenes volume)
constexpr int   GX = 200, GY = 200, GZ = 16;
constexpr int   TOTAL = GX * GY * GZ;        // 640000 voxels
constexpr int   ND = 16;                     // feature dims
constexpr int   KW = 6;                      // reference window: start + [0,6)
constexpr float VS = 0.4f;
constexpr float VMINX = -40.0f, VMINY = -40.0f, VMINZ = -1.0f;

// Tiling: 4x4x4 voxel tiles; one WAVE per tile; block = (tx,ty) x 4 tz-waves.
constexpr int   TS = 4;
constexpr int   TX = 50, TY = 50, TZ = 4;    // 200/4, 200/4, 16/4
constexpr int   NT = TX * TY * TZ;           // 10000 tiles
constexpr int   REC = 32;                    // floats per packed gaussian record (128 B)
constexpr int   CAP = 128;                   // per-tile entry capacity (lambda~20, max~55)
constexpr int   BR  = 8;                     // records per staged batch: 8*128B = 64 lanes * 16B
constexpr float NHL2E = -0.72134752044448170f; // -0.5*log2(e): exp(-0.5*m) -> exp2(q)

// Record layout (floats):
//  [0..3]  mx, my, mz, opacity
//  [4..7]  q00, q01*2, q02*2, q11      (inverse cov pre-scaled by NHL2E)
//  [8..11] q12*2, q22, s_packed, e_packed   (bbox packed 8b/axis)
//  [12..15] spare
//  [16..31] features
// d_out layout: [density: TOTAL floats][feats: TOTAL*ND floats]
// d_ws layout:  [gdata: n*REC floats][counts: NT ints][entries: NT*CAP ints]

__global__ __launch_bounds__(256) void gv_prep(
    const float* __restrict__ means, const float* __restrict__ covs,
    const float* __restrict__ opac,  const float* __restrict__ feats,
    float* __restrict__ gdata, int* __restrict__ counts,
    int* __restrict__ entries, int n)
{
    int g = blockIdx.x * 256 + threadIdx.x;
    if (g >= n) return;
    const float* cv = covs + (size_t)g * 9;
    // symmetric 3x3: [[a,b,c],[b,d,e],[c,e,f]]
    float a = cv[0], b = cv[1], c = cv[2], d = cv[4], e = cv[5], f = cv[8];
    float A = d * f - e * e;
    float B = c * e - b * f;
    float C = b * e - c * d;
    float invdet = 1.0f / (a * A + b * B + c * C);
    float mx = means[g * 3 + 0], my = means[g * 3 + 1], mz = means[g * 3 + 2];
    float rx = 3.0f * sqrtf(a), ry = 3.0f * sqrtf(d), rz = 3.0f * sqrtf(f);
    // trunc-toward-zero matches .astype(int32)
    int sx = max(0, (int)((mx - rx - VMINX) / VS));
    int sy = max(0, (int)((my - ry - VMINY) / VS));
    int sz = max(0, (int)((mz - rz - VMINZ) / VS));
    // reference window is start + [0,KW) masked by end -> clamp end to start+KW
    int ex = min(GX, (int)((mx + rx - VMINX) / VS) + 1); ex = min(ex, sx + KW);
    int ey = min(GY, (int)((my + ry - VMINY) / VS) + 1); ey = min(ey, sy + KW);
    int ez = min(GZ, (int)((mz + rz - VMINZ) / VS) + 1); ez = min(ez, sz + KW);

    float rec[REC];
    rec[0] = mx; rec[1] = my; rec[2] = mz; rec[3] = opac[g];
    rec[4] = (A * invdet) * NHL2E;                        // q00
    rec[5] = (B * invdet) * (2.0f * NHL2E);               // q01 (doubled)
    rec[6] = (C * invdet) * (2.0f * NHL2E);               // q02 (doubled)
    rec[7] = ((a * f - c * c) * invdet) * NHL2E;          // q11
    rec[8] = ((b * c - a * e) * invdet) * (2.0f * NHL2E); // q12 (doubled)
    rec[9] = ((a * d - b * b) * invdet) * NHL2E;          // q22
    rec[10] = __int_as_float(sx | (sy << 8) | (sz << 16));
    rec[11] = __int_as_float(ex | (ey << 8) | (ez << 16));
    rec[12] = 0.0f; rec[13] = 0.0f; rec[14] = 0.0f; rec[15] = 0.0f;
    const float4* f4 = (const float4*)(feats + (size_t)g * ND);
#pragma unroll
    for (int q = 0; q < 4; ++q) {
        float4 v = f4[q];
        rec[16 + q * 4 + 0] = v.x; rec[16 + q * 4 + 1] = v.y;
        rec[16 + q * 4 + 2] = v.z; rec[16 + q * 4 + 3] = v.w;
    }
    float4* dst = (float4*)(gdata + (size_t)g * REC);   // 128B-aligned
#pragma unroll
    for (int q = 0; q < 8; ++q) dst[q] = ((const float4*)rec)[q];

    int tx0 = sx >> 2, tx1 = (ex - 1) >> 2;
    int ty0 = sy >> 2, ty1 = (ey - 1) >> 2;
    int tz0 = sz >> 2, tz1 = (ez - 1) >> 2;
    for (int tx = tx0; tx <= tx1; ++tx)
        for (int ty = ty0; ty <= ty1; ++ty)
            for (int tz = tz0; tz <= tz1; ++tz) {
                int tile = (tx * TY + ty) * TZ + tz;
                int slot = atomicAdd(&counts[tile], 1);
                if (slot < CAP) entries[(size_t)tile * CAP + slot] = g;
            }
}

// One WAVE per 4x4x4 tile (1 voxel/lane, 17 register accumulators). Records are
// staged in 8-record (1 KB) batches: lane i vector-loads the (i%8)-th 16B chunk
// of record (i/8) and ds_writes it to a per-wave LDS buffer; compute reads the
// records back at wave-uniform addresses (pure broadcast). Double-buffered with
// global data one batch ahead and entry ids two batches ahead, so all waits are
// in-order vmcnt (the round-4 s_load pipeline was defeated by SMEM's
// out-of-order completion forcing lgkmcnt(0) drains). Each voxel written
// exactly once with normalization fused -> no global atomics.
__global__ __launch_bounds__(256) void gv_tile(
    const float* __restrict__ gdata, const int* __restrict__ counts,
    const int* __restrict__ entries, float* __restrict__ out)
{
    const int blk  = blockIdx.x;          // 0..2499 = tx*TY+ty
    const int ty   = blk % TY;
    const int tx   = blk / TY;
    const int wv   = threadIdx.x >> 6;    // wave id = tz tile
    const int lane = threadIdx.x & 63;
    const int tile = (tx * TY + ty) * TZ + wv;

    __shared__ float sbuf[4][2][BR * REC];   // 4 waves x double buffer x 1 KB

    const int lz = lane & 3, ly = (lane >> 2) & 3, lx = lane >> 4;
    const int ix = tx * TS + lx, iy = ty * TS + ly, iz = wv * TS + lz;
    const float pxc = (float)ix * VS + VMINX;   // voxel CORNER coords
    const float pyc = (float)iy * VS + VMINY;
    const float pzc = (float)iz * VS + VMINZ;

    float accd = 0.0f;
    float accf[ND];
#pragma unroll
    for (int c = 0; c < ND; ++c) accf[c] = 0.0f;
    accf[ND - 1] = 1e-5f;                       // reference: grid_feats[:, -1] = 1e-5

    // wave-uniform count -> force scalar so the batch loop is scalar-shaped
    const int cnt = __builtin_amdgcn_readfirstlane(min(counts[tile], CAP));
    const int* __restrict__ el = entries + (size_t)tile * CAP;

    const int rlane = lane >> 3;               // record slot within batch (0..7)
    const int flane = lane & 7;                // 16B chunk within record (0..7)
    const int wslot = rlane * REC + flane * 4; // float offset of this lane's chunk

    if (cnt > 0) {
        const int nb = (cnt + BR - 1) >> 3;
        float* b0 = &sbuf[wv][0][0];
        float* b1 = &sbuf[wv][1][0];

        // Prologue: stage batch 0; prefetch batch 1 data + batch 2 ids.
        int id0 = el[min(rlane, cnt - 1)];
        float4 v0 = *(const float4*)(gdata + (size_t)id0 * REC + flane * 4);
        *(float4*)(b0 + wslot) = v0;
        int idn = el[min(BR + rlane, cnt - 1)];
        float4 vn = *(const float4*)(gdata + (size_t)idn * REC + flane * 4);
        int idn2 = el[min(2 * BR + rlane, cnt - 1)];

        for (int b = 0; b < nb; ++b) {
            if (b + 1 < nb) {
                float* dst = ((b + 1) & 1) ? b1 : b0;
                *(float4*)(dst + wslot) = vn;                 // stage batch b+1
                vn = *(const float4*)(gdata + (size_t)idn2 * REC + flane * 4);
                idn2 = el[min((b + 3) * BR + rlane, cnt - 1)];
            }
            const float* rb = (b & 1) ? b1 : b0;
            const int rn = min(BR, cnt - b * BR);
            for (int r = 0; r < rn; ++r) {
                const float* rec = rb + r * REC;              // wave-uniform -> broadcast
                float4 q2 = *(const float4*)(rec + 8);        // q12, q22, s_pk, e_pk
                int spk = __float_as_int(q2.z), epk = __float_as_int(q2.w);
                int sx = spk & 255, sy = (spk >> 8) & 255, sz = (spk >> 16) & 255;
                int ex = epk & 255, ey = (epk >> 8) & 255, ez = (epk >> 16) & 255;
                bool in = (ix >= sx) & (ix < ex)
                        & (iy >= sy) & (iy < ey)
                        & (iz >= sz) & (iz < ez);
                if (__any(in)) {
                    float4 m  = *(const float4*)(rec);        // mx,my,mz,op
                    float4 q0 = *(const float4*)(rec + 4);    // q00,q01,q02,q11
                    float px = pxc - m.x;
                    float py = pyc - m.y;
                    float pz = pzc - m.z;
                    float q = q0.x * px * px + q0.w * py * py + q2.y * pz * pz
                            + q0.y * px * py + q0.z * px * pz + q2.x * py * pz;
                    float dens = m.w * __builtin_amdgcn_exp2f(q);
                    dens = in ? dens : 0.0f;
                    accd += dens;
                    float4 f0 = *(const float4*)(rec + 16);
                    float4 f1 = *(const float4*)(rec + 20);
                    float4 f2 = *(const float4*)(rec + 24);
                    float4 f3 = *(const float4*)(rec + 28);
                    accf[0]  = fmaf(dens, f0.x, accf[0]);
                    accf[1]  = fmaf(dens, f0.y, accf[1]);
                    accf[2]  = fmaf(dens, f0.z, accf[2]);
                    accf[3]  = fmaf(dens, f0.w, accf[3]);
                    accf[4]  = fmaf(dens, f1.x, accf[4]);
                    accf[5]  = fmaf(dens, f1.y, accf[5]);
                    accf[6]  = fmaf(dens, f1.z, accf[6]);
                    accf[7]  = fmaf(dens, f1.w, accf[7]);
                    accf[8]  = fmaf(dens, f2.x, accf[8]);
                    accf[9]  = fmaf(dens, f2.y, accf[9]);
                    accf[10] = fmaf(dens, f2.z, accf[10]);
                    accf[11] = fmaf(dens, f2.w, accf[11]);
                    accf[12] = fmaf(dens, f3.x, accf[12]);
                    accf[13] = fmaf(dens, f3.y, accf[13]);
                    accf[14] = fmaf(dens, f3.z, accf[14]);
                    accf[15] = fmaf(dens, f3.w, accf[15]);
                }
            }
        }
    }

    // Epilogue: density (raw) + normalized features; each voxel exactly once.
    const int flat = (ix * GY + iy) * GZ + iz;
    out[flat] = accd;
    float inv = 1.0f / fmaxf(accd, 1e-6f);      // clip(density, 1e-6, None)
    float4* fo = (float4*)(out + TOTAL + (size_t)flat * ND);
#pragma unroll
    for (int q = 0; q < 4; ++q) {
        float4 w;
        w.x = accf[q * 4 + 0] * inv;
        w.y = accf[q * 4 + 1] * inv;
        w.z = accf[q * 4 + 2] * inv;
        w.w = accf[q * 4 + 3] * inv;
        fo[q] = w;
    }
}

extern "C" void kernel_launch(void* const* d_in, const int* in_sizes, int n_in,
                              void* d_out, int out_size, void* d_ws, size_t ws_size,
                              hipStream_t stream) {
    const float* means = (const float*)d_in[0];   // [N,3]
    const float* covs  = (const float*)d_in[1];   // [N,3,3]
    const float* opac  = (const float*)d_in[2];   // [N]
    const float* feats = (const float*)d_in[3];   // [N,16]
    float* out = (float*)d_out;                   // [TOTAL + TOTAL*ND]
    const int n = in_sizes[2];

    float* gdata   = (float*)d_ws;                            // n*REC floats (4 MB)
    int*   counts  = (int*)(gdata + (size_t)n * REC);         // NT ints
    int*   entries = counts + ((NT + 63) & ~63);              // NT*CAP ints (5.12 MB)

    hipMemsetAsync(counts, 0, NT * sizeof(int), stream);
    gv_prep<<<(n + 255) / 256, 256, 0, stream>>>(means, covs, opac, feats,
                                                 gdata, counts, entries, n);
    gv_tile<<<TX * TY, 256, 0, stream>>>(gdata, counts, entries, out);
}